// Round 1
// baseline (809.088 us; speedup 1.0000x reference)
//
#include <hip/hip_runtime.h>
#include <hip/hip_bf16.h>

typedef __bf16 bf16_t;
typedef __bf16 bf16x4 __attribute__((ext_vector_type(4)));
typedef __bf16 bf16x8 __attribute__((ext_vector_type(8)));
typedef float  f32x4  __attribute__((ext_vector_type(4)));

#define N_NODES 100000
#define F_INC   128
#define HDIM    256
#define NEDGE   1000000
#define ELL_CAP 48

// ---------------- zero a count array ----------------
__global__ void zero_cnt(int* __restrict__ cnt, int n) {
    int i = blockIdx.x * 256 + threadIdx.x;
    if (i < n) cnt[i] = 0;
}

// ---------------- detect edge-index storage: int32 (flag=0) vs int64 (flag=1) --------
// int64 node ids < 2^31 => every odd int32 slot is a zero high-word.
__global__ void detect_kernel(const int* __restrict__ eit, const int* __restrict__ eil,
                              int* __restrict__ flags) {
    int lane = threadIdx.x & 63;
    const int* p = (threadIdx.x < 64) ? eit : eil;
    int s = (p[2 * lane + 1] != 0) ? 1 : 0;
    #pragma unroll
    for (int off = 1; off < 64; off <<= 1) s += __shfl_xor(s, off, 64);
    if (lane == 0) flags[(threadIdx.x < 64) ? 0 : 1] = (s == 0) ? 1 : 0;
}

// ---------------- pre-pack W1 (fp32 [128x256]) into bf16 MFMA B-fragment order ---------
// wlay element t = ((nt*4+kk)*64 + lane)*8 + j  holds  W1[k= kk*32+q*8+j][n= nt*16+m]
__global__ void wprep_kernel(const float* __restrict__ W1, bf16_t* __restrict__ wlay) {
    int t = blockIdx.x * 256 + threadIdx.x;        // 0..32767
    int j = t & 7, lane = (t >> 3) & 63, kk = (t >> 9) & 3, nt = t >> 11;
    int m = lane & 15, q = lane >> 4;
    int k = kk * 32 + q * 8 + j;
    int n = nt * 16 + m;
    wlay[t] = (bf16_t)W1[k * HDIM + n];
}

// ---------------- xw = (x/||x||) @ W1; row-norm fused via cross-lane reduce ----------------
// one wave computes 16 rows x 256 cols. Lane holds A[m][k], k = kk*32+q*8+j.
__global__ __launch_bounds__(256) void gemm_kernel(const float* __restrict__ x,
                                                   const bf16_t* __restrict__ wlay,
                                                   bf16_t* __restrict__ xw) {
    int w = blockIdx.x * 4 + (threadIdx.x >> 6);
    if (w >= N_NODES / 16) return;                 // 6250 waves exactly
    int lane = threadIdx.x & 63;
    int m = lane & 15, q = lane >> 4;
    int r0 = w * 16;
    int row = r0 + m;
    const float4* xr = (const float4*)(x + (size_t)row * F_INC);
    float4 u[8];
    #pragma unroll
    for (int kk = 0; kk < 4; kk++) {
        u[2 * kk]     = xr[kk * 8 + q * 2];
        u[2 * kk + 1] = xr[kk * 8 + q * 2 + 1];
    }
    float ss = 0.f;
    #pragma unroll
    for (int j = 0; j < 8; j++)
        ss += u[j].x * u[j].x + u[j].y * u[j].y + u[j].z * u[j].z + u[j].w * u[j].w;
    // lanes {m, m+16, m+32, m+48} hold row `row`: reduce across q via xor 16, 32
    ss += __shfl_xor(ss, 16, 64);
    ss += __shfl_xor(ss, 32, 64);
    float rv = 1.0f / fmaxf(sqrtf(ss), 1e-12f);
    bf16x8 a[4];
    #pragma unroll
    for (int kk = 0; kk < 4; kk++) {
        float4 p0 = u[2 * kk], p1 = u[2 * kk + 1];
        a[kk][0] = (bf16_t)(p0.x * rv); a[kk][1] = (bf16_t)(p0.y * rv);
        a[kk][2] = (bf16_t)(p0.z * rv); a[kk][3] = (bf16_t)(p0.w * rv);
        a[kk][4] = (bf16_t)(p1.x * rv); a[kk][5] = (bf16_t)(p1.y * rv);
        a[kk][6] = (bf16_t)(p1.z * rv); a[kk][7] = (bf16_t)(p1.w * rv);
    }
    const bf16x8* wl = (const bf16x8*)wlay;
    #pragma unroll
    for (int nt = 0; nt < 16; nt++) {
        f32x4 c = {0.f, 0.f, 0.f, 0.f};
        c = __builtin_amdgcn_mfma_f32_16x16x32_bf16(a[0], wl[(nt * 4 + 0) * 64 + lane], c, 0, 0, 0);
        c = __builtin_amdgcn_mfma_f32_16x16x32_bf16(a[1], wl[(nt * 4 + 1) * 64 + lane], c, 0, 0, 0);
        c = __builtin_amdgcn_mfma_f32_16x16x32_bf16(a[2], wl[(nt * 4 + 2) * 64 + lane], c, 0, 0, 0);
        c = __builtin_amdgcn_mfma_f32_16x16x32_bf16(a[3], wl[(nt * 4 + 3) * 64 + lane], c, 0, 0, 0);
        // C/D layout: col = lane&15, row = (lane>>4)*4 + reg
        #pragma unroll
        for (int i = 0; i < 4; i++) {
            xw[(size_t)(r0 + q * 4 + i) * HDIM + nt * 16 + m] = (bf16_t)c[i];
        }
    }
}

// ---------------- count-only degree pass (graph-last, for dinv_l) ----------------
__global__ void count_edges(const int* __restrict__ ei, const int* __restrict__ flag,
                            int* __restrict__ cnt) {
    int e = blockIdx.x * 256 + threadIdx.x;
    if (e >= NEDGE) return;
    int f = *flag;
    int dst = ei[(NEDGE + e) << f];
    atomicAdd(&cnt[dst], 1);
}

// ---------------- build padded ELL adjacency (dst -> list of src) ----------------
__global__ void fill_ell(const int* __restrict__ ei, const int* __restrict__ flag,
                         int* __restrict__ cnt, int* __restrict__ ell) {
    int e = blockIdx.x * 256 + threadIdx.x;
    if (e >= NEDGE) return;
    int f = *flag;                                  // 0: int32 layout, 1: int64 layout
    int src = ei[e << f];
    int dst = ei[(NEDGE + e) << f];
    int slot = atomicAdd(&cnt[dst], 1);
    if (slot < ELL_CAP) ell[dst * ELL_CAP + slot] = src;
}

// ---------------- dinv = rsqrt(deg+1) for both graphs ----------------
__global__ void dinv_kernel(const int* __restrict__ cnt_t, const int* __restrict__ cnt_l,
                            float* __restrict__ dt, float* __restrict__ dl) {
    int i = blockIdx.x * 256 + threadIdx.x;
    if (i >= N_NODES) return;
    dt[i] = rsqrtf((float)cnt_t[i] + 1.0f);
    dl[i] = rsqrtf((float)cnt_l[i] + 1.0f);
}

// ---------------- gather conv: one wave per dst node, 4 ch/lane, fp32 out (+opt bf16 copy) ---
// out[i] = dinv[i] * ( sum_e dinv[src_e]*xw[src_e] + dinv[i]*xw[i] ) + b1
__global__ __launch_bounds__(256) void gather_kernel(const int* __restrict__ ell,
                                                     const int* __restrict__ cnt,
                                                     const float* __restrict__ dinv,
                                                     const bf16_t* __restrict__ xw,
                                                     const float* __restrict__ b1,
                                                     float* __restrict__ out,
                                                     bf16_t* __restrict__ zb) {
    int i = blockIdx.x * 4 + (threadIdx.x >> 6);
    if (i >= N_NODES) return;
    int lane = threadIdx.x & 63;
    float di = dinv[i];
    const bf16x4* xws = (const bf16x4*)xw;         // row r at index r*64 + lane
    bf16x4 sv = xws[(size_t)i * 64 + lane];
    float acc0 = di * (float)sv.x;
    float acc1 = di * (float)sv.y;
    float acc2 = di * (float)sv.z;
    float acc3 = di * (float)sv.w;
    int deg = cnt[i];
    if (deg > ELL_CAP) deg = ELL_CAP;
    const int4* el4 = (const int4*)(ell + i * ELL_CAP);   // 192B rows, 16B aligned
    for (int b = 0; b < deg; b += 4) {
        int4 s = el4[b >> 2];
        int n = deg - b;                            // wave-uniform
        {
            float ds = dinv[s.x]; bf16x4 v = xws[(size_t)s.x * 64 + lane];
            acc0 += ds * (float)v.x; acc1 += ds * (float)v.y;
            acc2 += ds * (float)v.z; acc3 += ds * (float)v.w;
        }
        if (n > 1) {
            float ds = dinv[s.y]; bf16x4 v = xws[(size_t)s.y * 64 + lane];
            acc0 += ds * (float)v.x; acc1 += ds * (float)v.y;
            acc2 += ds * (float)v.z; acc3 += ds * (float)v.w;
        }
        if (n > 2) {
            float ds = dinv[s.z]; bf16x4 v = xws[(size_t)s.z * 64 + lane];
            acc0 += ds * (float)v.x; acc1 += ds * (float)v.y;
            acc2 += ds * (float)v.z; acc3 += ds * (float)v.w;
        }
        if (n > 3) {
            float ds = dinv[s.w]; bf16x4 v = xws[(size_t)s.w * 64 + lane];
            acc0 += ds * (float)v.x; acc1 += ds * (float)v.y;
            acc2 += ds * (float)v.z; acc3 += ds * (float)v.w;
        }
    }
    float4 bv = ((const float4*)b1)[lane];
    float4 o;
    o.x = di * acc0 + bv.x;
    o.y = di * acc1 + bv.y;
    o.z = di * acc2 + bv.z;
    o.w = di * acc3 + bv.w;
    ((float4*)out)[(size_t)i * 64 + lane] = o;
    if (zb) {
        bf16x4 zo;
        zo.x = (bf16_t)o.x; zo.y = (bf16_t)o.y; zo.z = (bf16_t)o.z; zo.w = (bf16_t)o.w;
        ((bf16x4*)zb)[(size_t)i * 64 + lane] = zo;
    }
}

// ---------------- aedge = sigmoid(<ztop[src], ztop[dst]>) from bf16 copy ----------------
// 16 lanes per edge, 4 edges per wave
__global__ __launch_bounds__(256) void aedge_kernel(const int* __restrict__ ei,
                                                    const int* __restrict__ flag,
                                                    const bf16_t* __restrict__ zb,
                                                    float* __restrict__ aedge) {
    int wid = blockIdx.x * 4 + (threadIdx.x >> 6);
    int lane = threadIdx.x & 63;
    int sub = lane & 15;
    int e = wid * 4 + (lane >> 4);                 // NEDGE % 4 == 0, grid exact
    int f = *flag;
    int src = ei[e << f];
    int dst = ei[(NEDGE + e) << f];
    const bf16x8* z8 = (const bf16x8*)zb;          // row r: 32 bf16x8 at r*32
    bf16x8 a0 = z8[(size_t)src * 32 + sub * 2];
    bf16x8 a1 = z8[(size_t)src * 32 + sub * 2 + 1];
    bf16x8 b0 = z8[(size_t)dst * 32 + sub * 2];
    bf16x8 b1 = z8[(size_t)dst * 32 + sub * 2 + 1];
    float p = 0.f;
    #pragma unroll
    for (int j = 0; j < 8; j++)
        p += (float)a0[j] * (float)b0[j] + (float)a1[j] * (float)b1[j];
    #pragma unroll
    for (int off = 1; off < 16; off <<= 1) p += __shfl_xor(p, off, 64);
    if (sub == 0) aedge[e] = 1.0f / (1.0f + __expf(-p));
}

extern "C" void kernel_launch(void* const* d_in, const int* in_sizes, int n_in,
                              void* d_out, int out_size, void* d_ws, size_t ws_size,
                              hipStream_t stream) {
    const float* x       = (const float*)d_in[0];
    const int*   ei_top  = (const int*)d_in[1];
    const int*   ei_last = (const int*)d_in[2];
    const float* W1      = (const float*)d_in[3];
    const float* b1      = (const float*)d_in[4];
    float* out = (float*)d_out;

    char* ws = (char*)d_ws;
    bf16_t* xw     = (bf16_t*)(ws);                  //  51,200,000 B
    bf16_t* zb     = (bf16_t*)(ws + 51200000);       //  51,200,000 B
    int*    ellA   = (int*)  (ws + 102400000);       //  19,200,000 B (shared: top, then last)
    float*  dinv_t = (float*)(ws + 121600000);       //     400,000 B
    float*  dinv_l = (float*)(ws + 122000000);       //     400,000 B
    int*    cnt_t  = (int*)  (ws + 122400000);       //     400,000 B
    int*    cnt_l  = (int*)  (ws + 122800000);       //     400,000 B (contiguous w/ cnt_t)
    bf16_t* wlay   = (bf16_t*)(ws + 123200000);      //      65,536 B
    int*    flags  = (int*)  (ws + 123265536);       //          64 B -> 123,265,600 total

    zero_cnt<<<(2 * N_NODES + 255) / 256, 256, 0, stream>>>(cnt_t, 2 * N_NODES);
    detect_kernel<<<1, 128, 0, stream>>>(ei_top, ei_last, flags);
    wprep_kernel<<<128, 256, 0, stream>>>(W1, wlay);
    fill_ell<<<(NEDGE + 255) / 256, 256, 0, stream>>>(ei_top, flags, cnt_t, ellA);
    count_edges<<<(NEDGE + 255) / 256, 256, 0, stream>>>(ei_last, flags + 1, cnt_l);
    dinv_kernel<<<(N_NODES + 255) / 256, 256, 0, stream>>>(cnt_t, cnt_l, dinv_t, dinv_l);
    gemm_kernel<<<(N_NODES / 16 + 3) / 4, 256, 0, stream>>>(x, wlay, xw);
    // graph-top conv -> out0 fp32 + zb bf16
    gather_kernel<<<N_NODES / 4, 256, 0, stream>>>(ellA, cnt_t, dinv_t, xw, b1, out, zb);
    // aedge from bf16 ztop copy
    aedge_kernel<<<NEDGE / 16, 256, 0, stream>>>(ei_top, flags, zb,
                                                 out + (size_t)2 * N_NODES * HDIM);
    // rebuild ELL region for graph-last (reuse cnt_t as slot counter)
    zero_cnt<<<(N_NODES + 255) / 256, 256, 0, stream>>>(cnt_t, N_NODES);
    fill_ell<<<(NEDGE + 255) / 256, 256, 0, stream>>>(ei_last, flags + 1, cnt_t, ellA);
    gather_kernel<<<N_NODES / 4, 256, 0, stream>>>(ellA, cnt_t, dinv_l, xw, b1,
                                                   out + (size_t)N_NODES * HDIM, (bf16_t*)0);
}

// Round 2
// 677.011 us; speedup vs baseline: 1.1951x; 1.1951x over previous
//
#include <hip/hip_runtime.h>
#include <hip/hip_bf16.h>

typedef __bf16 bf16_t;
typedef __bf16 bf16x4 __attribute__((ext_vector_type(4)));
typedef __bf16 bf16x8 __attribute__((ext_vector_type(8)));
typedef float  f32x4  __attribute__((ext_vector_type(4)));

#define N_NODES 100000
#define F_INC   128
#define HDIM    256
#define NEDGE   1000000
#define ELL_CAP 48
#define GATHER_BLKS (N_NODES / 4)        // 25000
#define AEDGE_BLKS  (NEDGE / 16)         // 62500
#define GEMM_BLKS   ((N_NODES / 16 + 3) / 4)  // 1563
#define FILL_BLKS   ((NEDGE + 255) / 256)     // 3907

// ---------------- zero a count array ----------------
__global__ void zero_cnt(int* __restrict__ cnt, int n) {
    int i = blockIdx.x * 256 + threadIdx.x;
    if (i < n) cnt[i] = 0;
}

// ---------------- detect edge-index storage: int32 (flag=0) vs int64 (flag=1) --------
__global__ void detect_kernel(const int* __restrict__ eit, const int* __restrict__ eil,
                              int* __restrict__ flags) {
    int lane = threadIdx.x & 63;
    const int* p = (threadIdx.x < 64) ? eit : eil;
    int s = (p[2 * lane + 1] != 0) ? 1 : 0;
    #pragma unroll
    for (int off = 1; off < 64; off <<= 1) s += __shfl_xor(s, off, 64);
    if (lane == 0) flags[(threadIdx.x < 64) ? 0 : 1] = (s == 0) ? 1 : 0;
}

// ---------------- pre-pack W1 into bf16 MFMA B-fragment order; zero xw sentinel row ----
__global__ void wprep_kernel(const float* __restrict__ W1, bf16_t* __restrict__ wlay,
                             bf16_t* __restrict__ xw) {
    int t = blockIdx.x * 256 + threadIdx.x;        // 0..32767
    if (blockIdx.x == 0) {
        // zero the sentinel row N_NODES of xw (256 bf16)
        xw[(size_t)N_NODES * HDIM + threadIdx.x] = (bf16_t)0.f;
    }
    int j = t & 7, lane = (t >> 3) & 63, kk = (t >> 9) & 3, nt = t >> 11;
    int m = lane & 15, q = lane >> 4;
    int k = kk * 32 + q * 8 + j;
    int n = nt * 16 + m;
    wlay[t] = (bf16_t)W1[k * HDIM + n];
}

// ---------------- gemm body: 16 rows x 256 cols per wave, row-norm fused ----------------
__device__ __forceinline__ void gemm_body(int w, int lane, const float* __restrict__ x,
                                          const bf16_t* __restrict__ wlay,
                                          bf16_t* __restrict__ xw) {
    if (w >= N_NODES / 16) return;                 // 6250 waves exactly
    int m = lane & 15, q = lane >> 4;
    int r0 = w * 16;
    int row = r0 + m;
    const float4* xr = (const float4*)(x + (size_t)row * F_INC);
    float4 u[8];
    #pragma unroll
    for (int kk = 0; kk < 4; kk++) {
        u[2 * kk]     = xr[kk * 8 + q * 2];
        u[2 * kk + 1] = xr[kk * 8 + q * 2 + 1];
    }
    float ss = 0.f;
    #pragma unroll
    for (int j = 0; j < 8; j++)
        ss += u[j].x * u[j].x + u[j].y * u[j].y + u[j].z * u[j].z + u[j].w * u[j].w;
    ss += __shfl_xor(ss, 16, 64);
    ss += __shfl_xor(ss, 32, 64);
    float rv = 1.0f / fmaxf(sqrtf(ss), 1e-12f);
    bf16x8 a[4];
    #pragma unroll
    for (int kk = 0; kk < 4; kk++) {
        float4 p0 = u[2 * kk], p1 = u[2 * kk + 1];
        a[kk][0] = (bf16_t)(p0.x * rv); a[kk][1] = (bf16_t)(p0.y * rv);
        a[kk][2] = (bf16_t)(p0.z * rv); a[kk][3] = (bf16_t)(p0.w * rv);
        a[kk][4] = (bf16_t)(p1.x * rv); a[kk][5] = (bf16_t)(p1.y * rv);
        a[kk][6] = (bf16_t)(p1.z * rv); a[kk][7] = (bf16_t)(p1.w * rv);
    }
    const bf16x8* wl = (const bf16x8*)wlay;
    #pragma unroll
    for (int nt = 0; nt < 16; nt++) {
        f32x4 c = {0.f, 0.f, 0.f, 0.f};
        c = __builtin_amdgcn_mfma_f32_16x16x32_bf16(a[0], wl[(nt * 4 + 0) * 64 + lane], c, 0, 0, 0);
        c = __builtin_amdgcn_mfma_f32_16x16x32_bf16(a[1], wl[(nt * 4 + 1) * 64 + lane], c, 0, 0, 0);
        c = __builtin_amdgcn_mfma_f32_16x16x32_bf16(a[2], wl[(nt * 4 + 2) * 64 + lane], c, 0, 0, 0);
        c = __builtin_amdgcn_mfma_f32_16x16x32_bf16(a[3], wl[(nt * 4 + 3) * 64 + lane], c, 0, 0, 0);
        #pragma unroll
        for (int i = 0; i < 4; i++) {
            xw[(size_t)(r0 + q * 4 + i) * HDIM + nt * 16 + m] = (bf16_t)c[i];
        }
    }
}

// ---------------- build padded ELL adjacency (dst -> list of src); counter = degree ----
__device__ __forceinline__ void fill_body(int e, const int* __restrict__ ei,
                                          const int* __restrict__ flag,
                                          int* __restrict__ cnt, int* __restrict__ ell) {
    if (e >= NEDGE) return;
    int f = *flag;                                  // 0: int32 layout, 1: int64 layout
    int src = ei[e << f];
    int dst = ei[(NEDGE + e) << f];
    int slot = atomicAdd(&cnt[dst], 1);
    if (slot < ELL_CAP) ell[dst * ELL_CAP + slot] = src;
}

__global__ void fill_ell(const int* __restrict__ ei, const int* __restrict__ flag,
                         int* __restrict__ cnt, int* __restrict__ ell) {
    fill_body(blockIdx.x * 256 + threadIdx.x, ei, flag, cnt, ell);
}

// ---------------- FUSED-A: gemm + fill_ell(top) (independent work, one dispatch) --------
__global__ __launch_bounds__(256) void gemm_fill_kernel(const float* __restrict__ x,
                                                        const bf16_t* __restrict__ wlay,
                                                        bf16_t* __restrict__ xw,
                                                        const int* __restrict__ ei,
                                                        const int* __restrict__ flag,
                                                        int* __restrict__ cnt,
                                                        int* __restrict__ ell) {
    if (blockIdx.x < GEMM_BLKS) {
        gemm_body(blockIdx.x * 4 + (threadIdx.x >> 6), threadIdx.x & 63, x, wlay, xw);
    } else {
        fill_body((blockIdx.x - GEMM_BLKS) * 256 + threadIdx.x, ei, flag, cnt, ell);
    }
}

// ---------------- dinv = rsqrt(deg+1), sentinel slot, pad ELL rows to multiple of 4 ----
__global__ void dinvpad_kernel(const int* __restrict__ cnt, float* __restrict__ dinv,
                               int* __restrict__ ell) {
    int i = blockIdx.x * 256 + threadIdx.x;
    if (i >= N_NODES) {
        if (i == N_NODES) dinv[N_NODES] = 0.f;     // sentinel: zero weight
        return;
    }
    int c = cnt[i];
    dinv[i] = rsqrtf((float)c + 1.0f);
    int deg = (c > ELL_CAP) ? ELL_CAP : c;
    int r4 = (deg + 3) & ~3;
    for (int s = deg; s < r4; s++) ell[i * ELL_CAP + s] = N_NODES;
}

// ---------------- gather conv body: branch-free sentinel-padded loop --------------------
// out[i] = dinv[i] * ( sum_e dinv[src_e]*xw[src_e] + dinv[i]*xw[i] ) + b1
__device__ __forceinline__ void gather_body(int i, int lane, const int* __restrict__ ell,
                                            const int* __restrict__ cnt,
                                            const float* __restrict__ dinv,
                                            const bf16_t* __restrict__ xw,
                                            const float* __restrict__ b1,
                                            float* __restrict__ out,
                                            bf16_t* __restrict__ zb) {
    float di = dinv[i];
    const bf16x4* xws = (const bf16x4*)xw;         // row r at index r*64 + lane
    bf16x4 sv = xws[(size_t)i * 64 + lane];
    float acc0 = di * (float)sv.x;
    float acc1 = di * (float)sv.y;
    float acc2 = di * (float)sv.z;
    float acc3 = di * (float)sv.w;
    int deg = cnt[i];
    if (deg > ELL_CAP) deg = ELL_CAP;
    int nit = (deg + 3) >> 2;                      // padded with sentinel to mult of 4
    const int4* el4 = (const int4*)(ell + i * ELL_CAP);   // 192B rows, 16B aligned
    for (int b = 0; b < nit; b++) {
        int4 s = el4[b];
        float d0 = dinv[s.x], d1 = dinv[s.y], d2 = dinv[s.z], d3 = dinv[s.w];
        bf16x4 v0 = xws[(size_t)s.x * 64 + lane];
        bf16x4 v1 = xws[(size_t)s.y * 64 + lane];
        bf16x4 v2 = xws[(size_t)s.z * 64 + lane];
        bf16x4 v3 = xws[(size_t)s.w * 64 + lane];
        acc0 += d0 * (float)v0.x + d1 * (float)v1.x + d2 * (float)v2.x + d3 * (float)v3.x;
        acc1 += d0 * (float)v0.y + d1 * (float)v1.y + d2 * (float)v2.y + d3 * (float)v3.y;
        acc2 += d0 * (float)v0.z + d1 * (float)v1.z + d2 * (float)v2.z + d3 * (float)v3.z;
        acc3 += d0 * (float)v0.w + d1 * (float)v1.w + d2 * (float)v2.w + d3 * (float)v3.w;
    }
    float4 bv = ((const float4*)b1)[lane];
    float4 o;
    o.x = di * acc0 + bv.x;
    o.y = di * acc1 + bv.y;
    o.z = di * acc2 + bv.z;
    o.w = di * acc3 + bv.w;
    ((float4*)out)[(size_t)i * 64 + lane] = o;
    if (zb) {
        bf16x4 zo;
        zo.x = (bf16_t)o.x; zo.y = (bf16_t)o.y; zo.z = (bf16_t)o.z; zo.w = (bf16_t)o.w;
        ((bf16x4*)zb)[(size_t)i * 64 + lane] = zo;
    }
}

__global__ __launch_bounds__(256) void gather_top_kernel(const int* __restrict__ ell,
                                                         const int* __restrict__ cnt,
                                                         const float* __restrict__ dinv,
                                                         const bf16_t* __restrict__ xw,
                                                         const float* __restrict__ b1,
                                                         float* __restrict__ out,
                                                         bf16_t* __restrict__ zb) {
    gather_body(blockIdx.x * 4 + (threadIdx.x >> 6), threadIdx.x & 63,
                ell, cnt, dinv, xw, b1, out, zb);
}

// ---------------- aedge body: sigmoid(<ztop[src], ztop[dst]>), 16 lanes/edge ------------
__device__ __forceinline__ void aedge_body(int wid, int lane, const int* __restrict__ ei,
                                           const int* __restrict__ flag,
                                           const bf16_t* __restrict__ zb,
                                           float* __restrict__ aedge) {
    int sub = lane & 15;
    int e = wid * 4 + (lane >> 4);                 // NEDGE % 4 == 0, grid exact
    int f = *flag;
    int src = ei[e << f];
    int dst = ei[(NEDGE + e) << f];
    const bf16x8* z8 = (const bf16x8*)zb;          // row r: 32 bf16x8 at r*32
    bf16x8 a0 = z8[(size_t)src * 32 + sub * 2];
    bf16x8 a1 = z8[(size_t)src * 32 + sub * 2 + 1];
    bf16x8 b0 = z8[(size_t)dst * 32 + sub * 2];
    bf16x8 b1 = z8[(size_t)dst * 32 + sub * 2 + 1];
    float p = 0.f;
    #pragma unroll
    for (int j = 0; j < 8; j++)
        p += (float)a0[j] * (float)b0[j] + (float)a1[j] * (float)b1[j];
    #pragma unroll
    for (int off = 1; off < 16; off <<= 1) p += __shfl_xor(p, off, 64);
    if (sub == 0) aedge[e] = 1.0f / (1.0f + __expf(-p));
}

// ---------------- FUSED-C: gather(last) + aedge(top) in one dispatch --------------------
__global__ __launch_bounds__(256) void fused_last_kernel(const int* __restrict__ ell,
                                                         const int* __restrict__ cnt,
                                                         const float* __restrict__ dinv,
                                                         const bf16_t* __restrict__ xw,
                                                         const float* __restrict__ b1,
                                                         float* __restrict__ out1,
                                                         const int* __restrict__ ei_top,
                                                         const int* __restrict__ flags,
                                                         const bf16_t* __restrict__ zb,
                                                         float* __restrict__ aedge) {
    int lane = threadIdx.x & 63;
    if (blockIdx.x < GATHER_BLKS) {
        gather_body(blockIdx.x * 4 + (threadIdx.x >> 6), lane,
                    ell, cnt, dinv, xw, b1, out1, (bf16_t*)0);
    } else {
        aedge_body((blockIdx.x - GATHER_BLKS) * 4 + (threadIdx.x >> 6), lane,
                   ei_top, flags, zb, aedge);
    }
}

extern "C" void kernel_launch(void* const* d_in, const int* in_sizes, int n_in,
                              void* d_out, int out_size, void* d_ws, size_t ws_size,
                              hipStream_t stream) {
    const float* x       = (const float*)d_in[0];
    const int*   ei_top  = (const int*)d_in[1];
    const int*   ei_last = (const int*)d_in[2];
    const float* W1      = (const float*)d_in[3];
    const float* b1      = (const float*)d_in[4];
    float* out = (float*)d_out;

    char* ws = (char*)d_ws;
    bf16_t* xw     = (bf16_t*)(ws);                  //  51,200,512 B (+sentinel row), pad to 51,201,024
    bf16_t* zb     = (bf16_t*)(ws + 51201024);       //  51,200,000 B
    int*    ellA   = (int*)  (ws + 102401024);       //  19,200,000 B (shared: top, then last)
    float*  dinv_t = (float*)(ws + 121601024);       //     400,064 B (N+1 floats)
    float*  dinv_l = (float*)(ws + 122001088);       //     400,064 B
    int*    cnt_t  = (int*)  (ws + 122401152);       //     400,000 B
    int*    cnt_l  = (int*)  (ws + 122801152);       //     400,000 B (contiguous w/ cnt_t)
    bf16_t* wlay   = (bf16_t*)(ws + 123201152);      //      65,536 B
    int*    flags  = (int*)  (ws + 123266688);       //          64 B -> 123,266,752 total

    zero_cnt<<<(2 * N_NODES + 255) / 256, 256, 0, stream>>>(cnt_t, 2 * N_NODES);
    detect_kernel<<<1, 128, 0, stream>>>(ei_top, ei_last, flags);
    wprep_kernel<<<128, 256, 0, stream>>>(W1, wlay, xw);
    // gemm + fill_ell(top) fused (independent work)
    gemm_fill_kernel<<<GEMM_BLKS + FILL_BLKS, 256, 0, stream>>>(x, wlay, xw,
                                                                ei_top, flags, cnt_t, ellA);
    dinvpad_kernel<<<(N_NODES + 256) / 256 + 1, 256, 0, stream>>>(cnt_t, dinv_t, ellA);
    // graph-top conv -> out0 fp32 + zb bf16
    gather_top_kernel<<<GATHER_BLKS, 256, 0, stream>>>(ellA, cnt_t, dinv_t, xw, b1, out, zb);
    // rebuild ELL for graph-last; slot counter doubles as degree count (no count_edges pass)
    fill_ell<<<FILL_BLKS, 256, 0, stream>>>(ei_last, flags + 1, cnt_l, ellA);
    dinvpad_kernel<<<(N_NODES + 256) / 256 + 1, 256, 0, stream>>>(cnt_l, dinv_l, ellA);
    // gather(last) + aedge(top) fused: both latency-bound on disjoint arrays
    fused_last_kernel<<<GATHER_BLKS + AEDGE_BLKS, 256, 0, stream>>>(
        ellA, cnt_l, dinv_l, xw, b1, out + (size_t)N_NODES * HDIM,
        ei_top, flags, zb, out + (size_t)2 * N_NODES * HDIM);
}

// Round 4
// 637.873 us; speedup vs baseline: 1.2684x; 1.0614x over previous
//
#include <hip/hip_runtime.h>
#include <hip/hip_bf16.h>

typedef __bf16 bf16_t;
typedef __bf16 bf16x4 __attribute__((ext_vector_type(4)));
typedef __bf16 bf16x8 __attribute__((ext_vector_type(8)));
typedef float  f32x4  __attribute__((ext_vector_type(4)));

#define N_NODES 100000
#define F_INC   128
#define HDIM    256
#define NEDGE   1000000
#define ELL_CAP 48
#define GATHER_BLKS (N_NODES / 4)             // 25000
#define GEMM_BLKS   ((N_NODES / 16 + 3) / 4)  // 1563
#define FILL_BLKS   ((NEDGE + 255) / 256)     // 3907

// ---------------- zero a count array ----------------
__global__ void zero_cnt(int* __restrict__ cnt, int n) {
    int i = blockIdx.x * 256 + threadIdx.x;
    if (i < n) cnt[i] = 0;
}

// ---------------- detect edge-index storage: int32 (flag=0) vs int64 (flag=1) --------
__global__ void detect_kernel(const int* __restrict__ eit, const int* __restrict__ eil,
                              int* __restrict__ flags) {
    int lane = threadIdx.x & 63;
    const int* p = (threadIdx.x < 64) ? eit : eil;
    int s = (p[2 * lane + 1] != 0) ? 1 : 0;
    #pragma unroll
    for (int off = 1; off < 64; off <<= 1) s += __shfl_xor(s, off, 64);
    if (lane == 0) flags[(threadIdx.x < 64) ? 0 : 1] = (s == 0) ? 1 : 0;
}

// ---------------- pre-pack W1 into bf16 MFMA B-fragment order; zero sentinel rows ------
__global__ void wprep_kernel(const float* __restrict__ W1, bf16_t* __restrict__ wlay,
                             bf16_t* __restrict__ xw, bf16_t* __restrict__ zb) {
    int t = blockIdx.x * 256 + threadIdx.x;        // 0..32767
    if (blockIdx.x == 0) {
        xw[(size_t)N_NODES * HDIM + threadIdx.x] = (bf16_t)0.f;  // sentinel row
        zb[(size_t)N_NODES * HDIM + threadIdx.x] = (bf16_t)0.f;  // sentinel row
    }
    int j = t & 7, lane = (t >> 3) & 63, kk = (t >> 9) & 3, nt = t >> 11;
    int m = lane & 15, q = lane >> 4;
    int k = kk * 32 + q * 8 + j;
    int n = nt * 16 + m;
    wlay[t] = (bf16_t)W1[k * HDIM + n];
}

// ---------------- gemm body: 16 rows x 256 cols per wave, row-norm fused ----------------
__device__ __forceinline__ void gemm_body(int w, int lane, const float* __restrict__ x,
                                          const bf16_t* __restrict__ wlay,
                                          bf16_t* __restrict__ xw) {
    if (w >= N_NODES / 16) return;                 // 6250 waves exactly
    int m = lane & 15, q = lane >> 4;
    int r0 = w * 16;
    int row = r0 + m;
    const float4* xr = (const float4*)(x + (size_t)row * F_INC);
    float4 u[8];
    #pragma unroll
    for (int kk = 0; kk < 4; kk++) {
        u[2 * kk]     = xr[kk * 8 + q * 2];
        u[2 * kk + 1] = xr[kk * 8 + q * 2 + 1];
    }
    float ss = 0.f;
    #pragma unroll
    for (int j = 0; j < 8; j++)
        ss += u[j].x * u[j].x + u[j].y * u[j].y + u[j].z * u[j].z + u[j].w * u[j].w;
    ss += __shfl_xor(ss, 16, 64);
    ss += __shfl_xor(ss, 32, 64);
    float rv = 1.0f / fmaxf(sqrtf(ss), 1e-12f);
    bf16x8 a[4];
    #pragma unroll
    for (int kk = 0; kk < 4; kk++) {
        float4 p0 = u[2 * kk], p1 = u[2 * kk + 1];
        a[kk][0] = (bf16_t)(p0.x * rv); a[kk][1] = (bf16_t)(p0.y * rv);
        a[kk][2] = (bf16_t)(p0.z * rv); a[kk][3] = (bf16_t)(p0.w * rv);
        a[kk][4] = (bf16_t)(p1.x * rv); a[kk][5] = (bf16_t)(p1.y * rv);
        a[kk][6] = (bf16_t)(p1.z * rv); a[kk][7] = (bf16_t)(p1.w * rv);
    }
    const bf16x8* wl = (const bf16x8*)wlay;
    #pragma unroll
    for (int nt = 0; nt < 16; nt++) {
        f32x4 c = {0.f, 0.f, 0.f, 0.f};
        c = __builtin_amdgcn_mfma_f32_16x16x32_bf16(a[0], wl[(nt * 4 + 0) * 64 + lane], c, 0, 0, 0);
        c = __builtin_amdgcn_mfma_f32_16x16x32_bf16(a[1], wl[(nt * 4 + 1) * 64 + lane], c, 0, 0, 0);
        c = __builtin_amdgcn_mfma_f32_16x16x32_bf16(a[2], wl[(nt * 4 + 2) * 64 + lane], c, 0, 0, 0);
        c = __builtin_amdgcn_mfma_f32_16x16x32_bf16(a[3], wl[(nt * 4 + 3) * 64 + lane], c, 0, 0, 0);
        #pragma unroll
        for (int i = 0; i < 4; i++) {
            xw[(size_t)(r0 + q * 4 + i) * HDIM + nt * 16 + m] = (bf16_t)c[i];
        }
    }
}

// ---------------- ELL builders: paired (src,eid) for top; src-only for last -------------
__device__ __forceinline__ void fill2_body(int e, const int* __restrict__ ei,
                                           const int* __restrict__ flag,
                                           int* __restrict__ cnt, int* __restrict__ ell2) {
    if (e >= NEDGE) return;
    int f = *flag;
    int src = ei[e << f];
    int dst = ei[(NEDGE + e) << f];
    int slot = atomicAdd(&cnt[dst], 1);
    if (slot < ELL_CAP) {
        int2 pr; pr.x = src; pr.y = e;
        ((int2*)ell2)[(size_t)dst * ELL_CAP + slot] = pr;
    }
}

__device__ __forceinline__ void fill_body(int e, const int* __restrict__ ei,
                                          const int* __restrict__ flag,
                                          int* __restrict__ cnt, int* __restrict__ ell) {
    if (e >= NEDGE) return;
    int f = *flag;
    int src = ei[e << f];
    int dst = ei[(NEDGE + e) << f];
    int slot = atomicAdd(&cnt[dst], 1);
    if (slot < ELL_CAP) ell[dst * ELL_CAP + slot] = src;
}

// ---------------- FUSED-A: gemm + fill2(top) (independent work, one dispatch) -----------
__global__ __launch_bounds__(256) void gemm_fill_kernel(const float* __restrict__ x,
                                                        const bf16_t* __restrict__ wlay,
                                                        bf16_t* __restrict__ xw,
                                                        const int* __restrict__ ei,
                                                        const int* __restrict__ flag,
                                                        int* __restrict__ cnt,
                                                        int* __restrict__ ell2) {
    if (blockIdx.x < GEMM_BLKS) {
        gemm_body(blockIdx.x * 4 + (threadIdx.x >> 6), threadIdx.x & 63, x, wlay, xw);
    } else {
        fill2_body((blockIdx.x - GEMM_BLKS) * 256 + threadIdx.x, ei, flag, cnt, ell2);
    }
}

// ---------------- dinv = rsqrt(deg+1), sentinel slot, pad ELL rows to mult of 4 ---------
__global__ void dinvpad_kernel(const int* __restrict__ cnt, float* __restrict__ dinv,
                               int* __restrict__ ell, int paired) {
    int i = blockIdx.x * 256 + threadIdx.x;
    if (i >= N_NODES) {
        if (i == N_NODES) dinv[N_NODES] = 0.f;     // sentinel: zero weight
        return;
    }
    int c = cnt[i];
    dinv[i] = rsqrtf((float)c + 1.0f);
    int deg = (c > ELL_CAP) ? ELL_CAP : c;
    int r4 = (deg + 3) & ~3;
    if (paired) {
        int2 pr; pr.x = N_NODES; pr.y = -1;
        for (int s = deg; s < r4; s++) ((int2*)ell)[(size_t)i * ELL_CAP + s] = pr;
    } else {
        for (int s = deg; s < r4; s++) ell[i * ELL_CAP + s] = N_NODES;
    }
}

// ---------------- gather conv body: sentinel-padded, index-chunk software pipeline ------
// out[i] = dinv[i] * ( sum_e dinv[src_e]*xw[src_e] + dinv[i]*xw[i] ) + b1
template<bool PAIRED>
__device__ __forceinline__ void gather_body(int i, int lane, const int* __restrict__ ell,
                                            const int* __restrict__ cnt,
                                            const float* __restrict__ dinv,
                                            const bf16_t* __restrict__ xw,
                                            const float* __restrict__ b1,
                                            float* __restrict__ out,
                                            bf16_t* __restrict__ zb) {
    float di = dinv[i];
    const bf16x4* xws = (const bf16x4*)xw;         // row r at index r*64 + lane
    bf16x4 sv = xws[(size_t)i * 64 + lane];
    float acc0 = di * (float)sv.x;
    float acc1 = di * (float)sv.y;
    float acc2 = di * (float)sv.z;
    float acc3 = di * (float)sv.w;
    int deg = cnt[i];
    if (deg > ELL_CAP) deg = ELL_CAP;
    int nit = (deg + 3) >> 2;                      // padded with sentinel to mult of 4
    int4 sa, sb;                                   // current chunk (sa.x/.z,sb.x/.z if paired)
    if (PAIRED) {
        const int4* e8 = (const int4*)ell + (size_t)i * (ELL_CAP / 2);
        sa = e8[0]; sb = e8[1];
        for (int b = 0; b < nit; b++) {
            int bn = (b + 1 < nit) ? (b + 1) : b;
            int4 na = e8[2 * bn], nb = e8[2 * bn + 1];
            int s0 = sa.x, s1 = sa.z, s2 = sb.x, s3 = sb.z;
            float d0 = dinv[s0], d1 = dinv[s1], d2 = dinv[s2], d3 = dinv[s3];
            bf16x4 v0 = xws[(size_t)s0 * 64 + lane];
            bf16x4 v1 = xws[(size_t)s1 * 64 + lane];
            bf16x4 v2 = xws[(size_t)s2 * 64 + lane];
            bf16x4 v3 = xws[(size_t)s3 * 64 + lane];
            acc0 += d0 * (float)v0.x + d1 * (float)v1.x + d2 * (float)v2.x + d3 * (float)v3.x;
            acc1 += d0 * (float)v0.y + d1 * (float)v1.y + d2 * (float)v2.y + d3 * (float)v3.y;
            acc2 += d0 * (float)v0.z + d1 * (float)v1.z + d2 * (float)v2.z + d3 * (float)v3.z;
            acc3 += d0 * (float)v0.w + d1 * (float)v1.w + d2 * (float)v2.w + d3 * (float)v3.w;
            sa = na; sb = nb;
        }
    } else {
        const int4* el4 = (const int4*)(ell + (size_t)i * ELL_CAP);
        sa = el4[0];
        for (int b = 0; b < nit; b++) {
            int bn = (b + 1 < nit) ? (b + 1) : b;
            int4 na = el4[bn];
            int s0 = sa.x, s1 = sa.y, s2 = sa.z, s3 = sa.w;
            float d0 = dinv[s0], d1 = dinv[s1], d2 = dinv[s2], d3 = dinv[s3];
            bf16x4 v0 = xws[(size_t)s0 * 64 + lane];
            bf16x4 v1 = xws[(size_t)s1 * 64 + lane];
            bf16x4 v2 = xws[(size_t)s2 * 64 + lane];
            bf16x4 v3 = xws[(size_t)s3 * 64 + lane];
            acc0 += d0 * (float)v0.x + d1 * (float)v1.x + d2 * (float)v2.x + d3 * (float)v3.x;
            acc1 += d0 * (float)v0.y + d1 * (float)v1.y + d2 * (float)v2.y + d3 * (float)v3.y;
            acc2 += d0 * (float)v0.z + d1 * (float)v1.z + d2 * (float)v2.z + d3 * (float)v3.z;
            acc3 += d0 * (float)v0.w + d1 * (float)v1.w + d2 * (float)v2.w + d3 * (float)v3.w;
            sa = na;
        }
    }
    float4 bv = ((const float4*)b1)[lane];
    f32x4 o;
    o[0] = di * acc0 + bv.x;
    o[1] = di * acc1 + bv.y;
    o[2] = di * acc2 + bv.z;
    o[3] = di * acc3 + bv.w;
    // streaming store (nontemporal): keep L2/L3 for the gather hot set
    __builtin_nontemporal_store(o, (f32x4*)out + (size_t)i * 64 + lane);
    if (zb) {
        bf16x4 zo;
        zo.x = (bf16_t)o[0]; zo.y = (bf16_t)o[1]; zo.z = (bf16_t)o[2]; zo.w = (bf16_t)o[3];
        ((bf16x4*)zb)[(size_t)i * 64 + lane] = zo;                           // re-read: cached
    }
}

// ---------------- FUSED-B: gather(top) + fill_ell(last) -------------------------------
__global__ __launch_bounds__(256) void gather_fill_kernel(const int* __restrict__ ell2,
                                                          const int* __restrict__ cnt,
                                                          const float* __restrict__ dinv,
                                                          const bf16_t* __restrict__ xw,
                                                          const float* __restrict__ b1,
                                                          float* __restrict__ out,
                                                          bf16_t* __restrict__ zb,
                                                          const int* __restrict__ ei_l,
                                                          const int* __restrict__ flag_l,
                                                          int* __restrict__ cnt_l,
                                                          int* __restrict__ ell_l) {
    if (blockIdx.x < FILL_BLKS) {
        fill_body(blockIdx.x * 256 + threadIdx.x, ei_l, flag_l, cnt_l, ell_l);
    } else {
        gather_body<true>((blockIdx.x - FILL_BLKS) * 4 + (threadIdx.x >> 6), threadIdx.x & 63,
                          ell2, cnt, dinv, xw, b1, out, zb);
    }
}

// ---------------- aedge (dst-major): dst row loaded once per node ------------------------
// wave = one dst node; 4x 16-lane groups each handle one edge slot per iteration
__device__ __forceinline__ void aedge_dst_body(int i, int lane, const int* __restrict__ ell2,
                                               const int* __restrict__ cnt,
                                               const bf16_t* __restrict__ zb,
                                               float* __restrict__ aedge) {
    int sub = lane & 15, g = lane >> 4;
    const bf16x8* z8 = (const bf16x8*)zb;          // row r: 32 bf16x8 at r*32
    bf16x8 d0 = z8[(size_t)i * 32 + sub * 2];      // dst row: once per node
    bf16x8 d1 = z8[(size_t)i * 32 + sub * 2 + 1];
    int deg = cnt[i];
    if (deg > ELL_CAP) deg = ELL_CAP;
    int nit = (deg + 3) >> 2;
    if (nit == 0) return;
    const int2* pr = (const int2*)ell2 + (size_t)i * ELL_CAP;
    int2 pe = pr[g];
    for (int b = 0; b < nit; b++) {
        int bn = (b + 1 < nit) ? (b + 1) : b;
        int2 pn = pr[bn * 4 + g];
        int src = pe.x, eid = pe.y;
        bf16x8 a0 = z8[(size_t)src * 32 + sub * 2];
        bf16x8 a1 = z8[(size_t)src * 32 + sub * 2 + 1];
        float p = 0.f;
        #pragma unroll
        for (int j = 0; j < 8; j++)
            p += (float)a0[j] * (float)d0[j] + (float)a1[j] * (float)d1[j];
        #pragma unroll
        for (int off = 1; off < 16; off <<= 1) p += __shfl_xor(p, off, 64);
        if (sub == 0 && eid >= 0)
            __builtin_nontemporal_store(1.0f / (1.0f + __expf(-p)), &aedge[eid]);
        pe = pn;
    }
}

// ---------------- FUSED-C: gather(last) + aedge-dst(top), parity-interleaved ------------
__global__ __launch_bounds__(256) void fused_last_kernel(const int* __restrict__ ell_l,
                                                         const int* __restrict__ cnt_l,
                                                         const float* __restrict__ dinv_l,
                                                         const bf16_t* __restrict__ xw,
                                                         const float* __restrict__ b1,
                                                         float* __restrict__ out1,
                                                         const int* __restrict__ ell2_t,
                                                         const int* __restrict__ cnt_t,
                                                         const bf16_t* __restrict__ zb,
                                                         float* __restrict__ aedge) {
    int lane = threadIdx.x & 63;
    int node = (blockIdx.x >> 1) * 4 + (threadIdx.x >> 6);
    if (blockIdx.x & 1) {
        aedge_dst_body(node, lane, ell2_t, cnt_t, zb, aedge);
    } else {
        gather_body<false>(node, lane, ell_l, cnt_l, dinv_l, xw, b1, out1, (bf16_t*)0);
    }
}

extern "C" void kernel_launch(void* const* d_in, const int* in_sizes, int n_in,
                              void* d_out, int out_size, void* d_ws, size_t ws_size,
                              hipStream_t stream) {
    const float* x       = (const float*)d_in[0];
    const int*   ei_top  = (const int*)d_in[1];
    const int*   ei_last = (const int*)d_in[2];
    const float* W1      = (const float*)d_in[3];
    const float* b1      = (const float*)d_in[4];
    float* out = (float*)d_out;

    char* ws = (char*)d_ws;
    bf16_t* xw     = (bf16_t*)(ws);                  //  51,200,512 B (+sentinel row)
    bf16_t* zb     = (bf16_t*)(ws + 51201024);       //  51,200,512 B (+sentinel row)
    int*    ell2t  = (int*)  (ws + 102402048);       //  38,400,000 B (src,eid pairs, top)
    int*    ell_l  = (int*)  (ws + 140802048);       //  19,200,000 B (src only, last)
    float*  dinv_t = (float*)(ws + 160002048);       //     400,064 B (N+1 floats)
    float*  dinv_l = (float*)(ws + 160402112);       //     400,064 B
    int*    cnt_t  = (int*)  (ws + 160802176);       //     400,000 B
    int*    cnt_l  = (int*)  (ws + 161202176);       //     400,000 B (contiguous w/ cnt_t)
    bf16_t* wlay   = (bf16_t*)(ws + 161602176);      //      65,536 B
    int*    flags  = (int*)  (ws + 161667712);       //          64 B -> 161,667,776 total

    zero_cnt<<<(2 * N_NODES + 255) / 256, 256, 0, stream>>>(cnt_t, 2 * N_NODES);
    detect_kernel<<<1, 128, 0, stream>>>(ei_top, ei_last, flags);
    wprep_kernel<<<128, 256, 0, stream>>>(W1, wlay, xw, zb);
    // gemm + fill2(top) fused (independent work)
    gemm_fill_kernel<<<GEMM_BLKS + FILL_BLKS, 256, 0, stream>>>(x, wlay, xw,
                                                                ei_top, flags, cnt_t, ell2t);
    dinvpad_kernel<<<(N_NODES + 256) / 256 + 1, 256, 0, stream>>>(cnt_t, dinv_t, ell2t, 1);
    // gather(top) -> out0 fp32 + zb bf16, fused with fill_ell(last)
    gather_fill_kernel<<<FILL_BLKS + GATHER_BLKS, 256, 0, stream>>>(
        ell2t, cnt_t, dinv_t, xw, b1, out, zb, ei_last, flags + 1, cnt_l, ell_l);
    dinvpad_kernel<<<(N_NODES + 256) / 256 + 1, 256, 0, stream>>>(cnt_l, dinv_l, ell_l, 0);
    // gather(last) + aedge-dst(top): parity-interleaved, disjoint arrays
    fused_last_kernel<<<2 * GATHER_BLKS, 256, 0, stream>>>(
        ell_l, cnt_l, dinv_l, xw, b1, out + (size_t)N_NODES * HDIM,
        ell2t, cnt_t, zb, out + (size_t)2 * N_NODES * HDIM);
}